// Round 2
// baseline (50.551 us; speedup 1.0000x reference)
//
#include <hip/hip_runtime.h>
#include <math.h>

// out[m] = s*(1-s) * (W[m,:] @ (x_f - x_i)),  s = sigmoid(W[m,:] @ x_i + b[m])
// D = M = 8192, W fp32 row-major. HBM-bound on the single pass over W.
//
// R2 change: 2 rows per wave so each LDS read of (x_i, v) feeds 2 rows of W
// — halves LDS traffic per W-byte (R1 analysis: LDS pipe was co-critical
// with HBM at 1 row/wave).

constexpr int D_DIM = 8192;
constexpr int BLOCK = 512;            // 8 waves
constexpr int ROWS_PER_WAVE = 2;
constexpr int ROWS_PER_BLOCK = (BLOCK / 64) * ROWS_PER_WAVE;  // 16

__global__ __launch_bounds__(BLOCK)
void dyn_fused_kernel(const float* __restrict__ x_i,
                      const float* __restrict__ x_f,
                      const float* __restrict__ W,
                      const float* __restrict__ b,
                      float* __restrict__ out,
                      int M)
{
    __shared__ float s_xi[D_DIM];   // 32 KiB
    __shared__ float s_v[D_DIM];    // 32 KiB

    const int tid = threadIdx.x;
    constexpr int NCHUNK = D_DIM / 4;   // 2048 float4 per vector

    // Stage x_i and v = x_f - x_i into LDS.
    const float4* xi_g = reinterpret_cast<const float4*>(x_i);
    const float4* xf_g = reinterpret_cast<const float4*>(x_f);
    float4* sxi_w = reinterpret_cast<float4*>(s_xi);
    float4* sv_w  = reinterpret_cast<float4*>(s_v);
    #pragma unroll
    for (int c = tid; c < NCHUNK; c += BLOCK) {
        float4 a = xi_g[c];
        float4 f = xf_g[c];
        sxi_w[c] = a;
        sv_w[c]  = make_float4(f.x - a.x, f.y - a.y, f.z - a.z, f.w - a.w);
    }
    __syncthreads();

    const int wave = tid >> 6;
    const int lane = tid & 63;
    const int row0 = blockIdx.x * ROWS_PER_BLOCK + wave * ROWS_PER_WAVE;
    if (row0 >= M) return;

    const float4* W0 = reinterpret_cast<const float4*>(W + (size_t)row0 * D_DIM);
    const float4* W1 = reinterpret_cast<const float4*>(W + (size_t)(row0 + 1) * D_DIM);
    const float4* sxi = reinterpret_cast<const float4*>(s_xi);
    const float4* sv  = reinterpret_cast<const float4*>(s_v);

    float acc_i0 = 0.0f, acc_v0 = 0.0f;
    float acc_i1 = 0.0f, acc_v1 = 0.0f;
    #pragma unroll 4
    for (int c = lane; c < NCHUNK; c += 64) {
        float4 w0 = W0[c];     // coalesced 1 KiB per wave instruction
        float4 w1 = W1[c];
        float4 xi = sxi[c];    // conflict-free ds_read_b128, shared by 2 rows
        float4 vv = sv[c];
        acc_i0 = fmaf(w0.x, xi.x, acc_i0);
        acc_i0 = fmaf(w0.y, xi.y, acc_i0);
        acc_i0 = fmaf(w0.z, xi.z, acc_i0);
        acc_i0 = fmaf(w0.w, xi.w, acc_i0);
        acc_v0 = fmaf(w0.x, vv.x, acc_v0);
        acc_v0 = fmaf(w0.y, vv.y, acc_v0);
        acc_v0 = fmaf(w0.z, vv.z, acc_v0);
        acc_v0 = fmaf(w0.w, vv.w, acc_v0);
        acc_i1 = fmaf(w1.x, xi.x, acc_i1);
        acc_i1 = fmaf(w1.y, xi.y, acc_i1);
        acc_i1 = fmaf(w1.z, xi.z, acc_i1);
        acc_i1 = fmaf(w1.w, xi.w, acc_i1);
        acc_v1 = fmaf(w1.x, vv.x, acc_v1);
        acc_v1 = fmaf(w1.y, vv.y, acc_v1);
        acc_v1 = fmaf(w1.z, vv.z, acc_v1);
        acc_v1 = fmaf(w1.w, vv.w, acc_v1);
    }

    // 64-lane butterfly reduction of all four accumulators.
    #pragma unroll
    for (int off = 32; off > 0; off >>= 1) {
        acc_i0 += __shfl_down(acc_i0, off, 64);
        acc_v0 += __shfl_down(acc_v0, off, 64);
        acc_i1 += __shfl_down(acc_i1, off, 64);
        acc_v1 += __shfl_down(acc_v1, off, 64);
    }

    if (lane == 0) {
        float z0 = acc_i0 + b[row0];
        float s0 = 1.0f / (1.0f + expf(-z0));
        out[row0] = s0 * (1.0f - s0) * acc_v0;
        float z1 = acc_i1 + b[row0 + 1];
        float s1 = 1.0f / (1.0f + expf(-z1));
        out[row0 + 1] = s1 * (1.0f - s1) * acc_v1;
    }
}

extern "C" void kernel_launch(void* const* d_in, const int* in_sizes, int n_in,
                              void* d_out, int out_size, void* d_ws, size_t ws_size,
                              hipStream_t stream) {
    // setup_inputs order: t(1), y(M), x_i(D), x_f(D), W(M*D), b(M)
    const float* x_i = (const float*)d_in[2];
    const float* x_f = (const float*)d_in[3];
    const float* W   = (const float*)d_in[4];
    const float* b   = (const float*)d_in[5];
    float* out = (float*)d_out;
    const int M = out_size;   // 8192

    const int grid = (M + ROWS_PER_BLOCK - 1) / ROWS_PER_BLOCK;  // 512
    dyn_fused_kernel<<<grid, BLOCK, 0, stream>>>(x_i, x_f, W, b, out, M);
}